// Round 19
// baseline (92.236 us; speedup 1.0000x reference)
//
#include <hip/hip_runtime.h>
#include <hip/hip_bf16.h>
#include <hip/hip_cooperative_groups.h>
#include <stdint.h>

#define Dm 128
#define BTOT (32 * 2048)

typedef short s16x8 __attribute__((ext_vector_type(8)));
typedef float f32x4 __attribute__((ext_vector_type(4)));

__device__ float g_Wq[Dm * Dm];   // Wq_c[g][d] = sum_f wq[g][f] * p_w2[f][d]
__device__ float g_Wk[Dm * Dm];
__device__ float g_bq[Dm], g_bk[Dm];
__device__ float g_u[Dm], g_w[Dm], g_c[1];
// frag buffer (shorts): [0,16384) M (32 slots), [16384,24576) W2f (16 slots), [24576,32768) W1f (16 slots)
__device__ __align__(16) unsigned short g_AllFrag[32768];

__device__ __forceinline__ float fast_sigmoid(float x) { return 1.0f / (1.0f + __expf(-x)); }
__device__ __forceinline__ float fast_tanh(float x) { return 1.0f - 2.0f / (__expf(2.0f * x) + 1.0f); }

__device__ __forceinline__ unsigned short f2bf(float f) {  // RNE f32->bf16 (precompute only)
    unsigned u = __float_as_uint(f);
    u += 0x7fffu + ((u >> 16) & 1u);
    return (unsigned short)(u >> 16);
}

__device__ __forceinline__ unsigned pk2(float lo, float hi) {  // 2×f32 -> packed 2×bf16 (RNE fptrunc)
    unsigned short ua = __builtin_bit_cast(unsigned short, (__bf16)lo);
    unsigned short ub = __builtin_bit_cast(unsigned short, (__bf16)hi);
    return (unsigned)ua | ((unsigned)ub << 16);
}

__device__ __forceinline__ s16x8 mk8(unsigned a, unsigned b, unsigned c, unsigned d) {
    union { unsigned u[4]; s16x8 v; } t;
    t.u[0] = a; t.u[1] = b; t.u[2] = c; t.u[3] = d;
    return t.v;
}

// rpf + sj for one wave's 2 positions (16 cols), k-map f(g,j)=4g+(j&3)+16*(j>>2).
__device__ __forceinline__ void compute_rpf(float xv, int g,
                                            const float* __restrict__ p_w1,
                                            const float* __restrict__ p_b1,
                                            s16x8* rpf, float& sj_out) {
    float sj = 0.f;
#pragma unroll
    for (int kc = 0; kc < 4; ++kc) {
        unsigned wds[4];
#pragma unroll
        for (int jh = 0; jh < 2; ++jh) {
            const int d4 = kc * 32 + 4 * g + 16 * jh;
            f32x4 w1v = *(const f32x4*)&p_w1[d4];
            f32x4 b1v = *(const f32x4*)&p_b1[d4];
            f32x4 wvv = *(const f32x4*)&g_w[d4];
            float v[4];
#pragma unroll
            for (int jj = 0; jj < 4; ++jj) {
                float val = fmaxf(fmaf(xv, w1v[jj], b1v[jj]), 0.f);
                sj = fmaf(wvv[jj], val, sj);
                v[jj] = val;
            }
            wds[jh * 2 + 0] = pk2(v[0], v[1]);
            wds[jh * 2 + 1] = pk2(v[2], v[3]);
        }
        rpf[kc] = mk8(wds[0], wds[1], wds[2], wds[3]);
    }
    sj += __shfl_xor(sj, 16);
    sj += __shfl_xor(sj, 32);
    sj_out = sj;
}

// Merged pre-kernel (cooperative): phase 1 = combine + W1f/W2f frags; grid sync;
// phase 2 = M frags + u/w/c. Saves one launch boundary vs separate k_pre1/k_pre2.
// 144 blocks x 128 thr << 256 CUs -> co-residency OK for cooperative launch.
__global__ __launch_bounds__(128) void k_pre_all(const float* __restrict__ wq,
                                                 const float* __restrict__ wk,
                                                 const float* __restrict__ pw2,
                                                 const float* __restrict__ pb2,
                                                 const float* __restrict__ ce_w1,
                                                 const float* __restrict__ ce_b1,
                                                 const float* __restrict__ ce_w2) {
    const int b = blockIdx.x, t = threadIdx.x;
    // ---- phase 1: blocks 0..127 combine; 128..135 W1f; 136..143 W2f ----
    if (b < 128) {
        const int g = b, d = t;
        float aq0 = 0.f, aq1 = 0.f, ak0 = 0.f, ak1 = 0.f;
#pragma unroll 8
        for (int f2 = 0; f2 < 64; ++f2) {
            float wqa = wq[g * Dm + 2 * f2], wqb = wq[g * Dm + 2 * f2 + 1];
            float wka = wk[g * Dm + 2 * f2], wkb = wk[g * Dm + 2 * f2 + 1];
            float pva = pw2[(2 * f2) * Dm + d], pvb = pw2[(2 * f2 + 1) * Dm + d];
            aq0 = fmaf(wqa, pva, aq0);
            aq1 = fmaf(wqb, pvb, aq1);
            ak0 = fmaf(wka, pva, ak0);
            ak1 = fmaf(wkb, pvb, ak1);
        }
        g_Wq[g * Dm + d] = aq0 + aq1;
        g_Wk[g * Dm + d] = ak0 + ak1;
        if (d == 0) {
            float bq0 = 0.f, bq1 = 0.f, bk0 = 0.f, bk1 = 0.f;
#pragma unroll 8
            for (int f2 = 0; f2 < 64; ++f2) {
                float pba = pb2[2 * f2], pbb = pb2[2 * f2 + 1];
                bq0 = fmaf(wq[g * Dm + 2 * f2], pba, bq0);
                bq1 = fmaf(wq[g * Dm + 2 * f2 + 1], pbb, bq1);
                bk0 = fmaf(wk[g * Dm + 2 * f2], pba, bk0);
                bk1 = fmaf(wk[g * Dm + 2 * f2 + 1], pbb, bk1);
            }
            g_bq[g] = bq0 + bq1;
            g_bk[g] = bk0 + bk1;
        }
    } else if (b < 136) {
        // W1f: slot s = rt*2+kc; row = 16rt+(l&15); k = kc*32+4g+(j&3)+16*(j>>2)
        const int s = (b - 128) * 128 + t;   // 0..1023
        const int l = s & 63, slot = s >> 6;
        const int rt = slot >> 1, kc = slot & 1;
        const int row = rt * 16 + (l & 15), gg = l >> 4;
#pragma unroll
        for (int j = 0; j < 8; ++j) {
            int k = kc * 32 + 4 * gg + (j & 3) + 16 * (j >> 2);
            float v = (k < 40) ? ce_w1[row * 40 + k] : ((k == 40) ? ce_b1[row] : 0.f);
            g_AllFrag[24576 + s * 8 + j] = f2bf(v);
        }
    } else {
        // W2f: slot = rt2*4+kc; o = 16rt2+(l&15)
        const int s = (b - 136) * 128 + t;
        const int l = s & 63, slot = s >> 6;
        const int rt2 = slot >> 2, kc = slot & 3;
        const int o = rt2 * 16 + (l & 15), gg = l >> 4;
#pragma unroll
        for (int j = 0; j < 8; ++j) {
            int k = kc * 32 + 4 * gg + (j & 3) + 16 * (j >> 2);
            g_AllFrag[16384 + s * 8 + j] = f2bf(ce_w2[o * Dm + k]);
        }
    }

    cooperative_groups::this_grid().sync();  // device-scope fence + barrier: g_Wq/g_Wk visible

    // ---- phase 2: blocks 0..127 M frags (one (slot,jj) each); block 128 u/w/c ----
    if (b < 128) {
        const int slot = b >> 2, jj = b & 3;
        const int kc = slot & 3, rt = slot >> 2;
        const int l = t & 63, jh = t >> 6;
        const int row = rt * 16 + (l & 15), g = l >> 4;
        const int e = kc * 32 + 4 * g + jj + 16 * jh;
        float a0 = 0.f, a1 = 0.f;
#pragma unroll 8
        for (int g2 = 0; g2 < 64; ++g2) {
            a0 = fmaf(g_Wq[(2 * g2) * Dm + row], g_Wk[(2 * g2) * Dm + e], a0);
            a1 = fmaf(g_Wq[(2 * g2 + 1) * Dm + row], g_Wk[(2 * g2 + 1) * Dm + e], a1);
        }
        g_AllFrag[(slot * 64 + l) * 8 + 4 * jh + jj] = f2bf(a0 + a1);
    } else if (b == 128) {
        const int d = t;
        float u0 = 0.f, u1 = 0.f, w0 = 0.f, w1 = 0.f;
#pragma unroll 8
        for (int g2 = 0; g2 < 64; ++g2) {
            u0 = fmaf(g_Wq[(2 * g2) * Dm + d], g_bk[2 * g2], u0);
            u1 = fmaf(g_Wq[(2 * g2 + 1) * Dm + d], g_bk[2 * g2 + 1], u1);
            w0 = fmaf(g_Wk[(2 * g2) * Dm + d], g_bq[2 * g2], w0);
            w1 = fmaf(g_Wk[(2 * g2 + 1) * Dm + d], g_bq[2 * g2 + 1], w1);
        }
        g_u[d] = u0 + u1;
        g_w[d] = w0 + w1;
        if (d == 0) {
            float c0 = 0.f, c1 = 0.f;
#pragma unroll 8
            for (int g2 = 0; g2 < 64; ++g2) {
                c0 = fmaf(g_bq[2 * g2], g_bk[2 * g2], c0);
                c1 = fmaf(g_bq[2 * g2 + 1], g_bk[2 * g2 + 1], c1);
            }
            g_c[0] = c0 + c1;
        }
    }
}

// Fused kernel (round-17 best, frozen): 256 thr = 4 waves; 16 positions/block;
// each wave owns 4 positions (2 rpf column-sets); M in LDS; Y/S per row-pair
// (4 Yacc live); s_setprio around the Y/S MFMA cluster.
__global__ __launch_bounds__(256) void k_fused(const float* __restrict__ x,
                                               const float* __restrict__ hist,
                                               const float* __restrict__ ce_b2,
                                               const float* __restrict__ p_w1,
                                               const float* __restrict__ p_b1,
                                               float* __restrict__ pred_out,
                                               float* __restrict__ A_out) {
    __shared__ __align__(16) unsigned short lds_m[16384];  // M frags, 32 KB
    __shared__ __align__(16) unsigned short lds_hB[2048];  // h in gate-B-frag layout, 4 KB
    __shared__ __align__(16) char lds_hg[16 * 41 * 4];     // union: hist f32 [16][41] / gateP u32 [16][33]
    float* lds_hist = (float*)lds_hg;
    unsigned* lds_gateP = (unsigned*)lds_hg;

    const int tid = threadIdx.x;
    const int wv = tid >> 6;       // 0..3
    const int l = tid & 63;
    const int g = l >> 4, c16 = l & 15;
    const long base = (long)blockIdx.x * 16;

    // ---- stage M frags via DMA: 4 waves x 8 KB ----
    {
        const char* gsrc = (const char*)g_AllFrag + (size_t)wv * 8192 + (size_t)l * 16;
        char* ldst = (char*)lds_m + wv * 8192;
#pragma unroll
        for (int q = 0; q < 8; ++q)
            __builtin_amdgcn_global_load_lds(
                (const __attribute__((address_space(1))) unsigned int*)(gsrc + q * 1024),
                (__attribute__((address_space(3))) unsigned int*)(ldst + q * 1024), 16, 0, 0);
    }
    // ---- stage hist (640 floats) ----
    {
        const float* hsrc = hist + base * 40;
        lds_hist[(tid / 40) * 41 + (tid % 40)] = hsrc[tid];
        int i2 = tid + 256;
        lds_hist[(i2 / 40) * 41 + (i2 % 40)] = hsrc[i2];
        if (tid < 128) {
            int i3 = tid + 512;
            lds_hist[(i3 / 40) * 41 + (i3 % 40)] = hsrc[i3];
        }
    }
    // ---- W frags to regs (dead after gate phase) ----
    s16x8 w1fA[2][2];
#pragma unroll
    for (int rr = 0; rr < 2; ++rr)
#pragma unroll
        for (int kc = 0; kc < 2; ++kc)
            w1fA[rr][kc] = *(const s16x8*)&g_AllFrag[24576 + (((2 * wv + rr) * 2 + kc) * 64 + l) * 8];
    s16x8 w2fA[4];
#pragma unroll
    for (int kc = 0; kc < 4; ++kc)
        w2fA[kc] = *(const s16x8*)&g_AllFrag[16384 + ((wv * 4 + kc) * 64 + l) * 8];
    f32x4 b2v = *(const f32x4*)&ce_b2[16 * wv + 4 * g];

    // ---- rpf for both column-sets (positions wv*4 + s*2 + np) ----
    const int np = c16 >> 3, i_me = c16 & 7;
    const float xv0 = x[(base + wv * 4 + 0 + np) * 8 + i_me];
    const float xv1 = x[(base + wv * 4 + 2 + np) * 8 + i_me];
    s16x8 rpf0[4], rpf1[4];
    float sj0, sj1;
    compute_rpf(xv0, g, p_w1, p_b1, rpf0, sj0);
    compute_rpf(xv1, g, p_w1, p_b1, rpf1, sj1);
    const float cc = g_c[0];

    __syncthreads();  // bar1: M DMA drained, hist visible

    // ---- hist B-frags (cols = 16 block positions; bias-1 at k=40) ----
    const float* hl = lds_hist + c16 * 41;
    s16x8 histB[2];
    histB[0] = mk8(pk2(hl[4 * g + 0], hl[4 * g + 1]),
                   pk2(hl[4 * g + 2], hl[4 * g + 3]),
                   pk2(hl[16 + 4 * g + 0], hl[16 + 4 * g + 1]),
                   pk2(hl[16 + 4 * g + 2], hl[16 + 4 * g + 3]));
    {
        float v[4];
#pragma unroll
        for (int jj = 0; jj < 4; ++jj) {
            int k = 32 + 4 * g + jj;
            int kk = (k < 40) ? k : 0;
            float t = hl[kk];
            t = (k < 40) ? t : 0.f;
            v[jj] = (k == 40) ? 1.f : t;       // bias column
        }
        histB[1] = mk8(pk2(v[0], v[1]), pk2(v[2], v[3]), 0u, 0u);
    }

    // ---- h MFMA: row-tiles rt = 2wv+rr; publish relu(h) in gate-B-frag layout ----
#pragma unroll
    for (int rr = 0; rr < 2; ++rr) {
        f32x4 hC = (f32x4){0.f, 0.f, 0.f, 0.f};
        hC = __builtin_amdgcn_mfma_f32_16x16x32_bf16(w1fA[rr][0], histB[0], hC, 0, 0, 0);
        hC = __builtin_amdgcn_mfma_f32_16x16x32_bf16(w1fA[rr][1], histB[1], hC, 0, 0, 0);
        unsigned* dst = (unsigned*)&lds_hB[(wv * 64 + l) * 8 + rr * 4];
        dst[0] = pk2(fmaxf(hC[0], 0.f), fmaxf(hC[1], 0.f));
        dst[1] = pk2(fmaxf(hC[2], 0.f), fmaxf(hC[3], 0.f));
    }

    __syncthreads();  // bar2: hB visible; hist reads done -> gate may overwrite lds_hg

    // ---- gate MFMA: wave wv owns o-rows 16wv..16wv+15 -> packed bf16 lds_gateP ----
    {
        s16x8 gB[4];
#pragma unroll
        for (int kc = 0; kc < 4; ++kc)
            gB[kc] = *(const s16x8*)&lds_hB[(kc * 64 + l) * 8];
        f32x4 gC = b2v;
#pragma unroll
        for (int kc = 0; kc < 4; ++kc)
            gC = __builtin_amdgcn_mfma_f32_16x16x32_bf16(w2fA[kc], gB[kc], gC, 0, 0, 0);
        unsigned* gp = lds_gateP + c16 * 33 + 8 * wv + 2 * g;
        gp[0] = pk2(fast_sigmoid(gC[0]), fast_sigmoid(gC[1]));
        gp[1] = pk2(fast_sigmoid(gC[2]), fast_sigmoid(gC[3]));
    }

    // ---- Y/S fused per row-pair: only 4 Yacc live at a time (16 VGPR) ----
    __builtin_amdgcn_s_setprio(1);
    f32x4 Sacc0 = (f32x4){0.f, 0.f, 0.f, 0.f};
    f32x4 Sacc1 = (f32x4){0.f, 0.f, 0.f, 0.f};
#pragma unroll
    for (int rt = 0; rt < 4; ++rt) {
        const int r0 = 2 * rt, r1 = 2 * rt + 1;
        f32x4 uv0 = *(const f32x4*)&g_u[16 * r0 + 4 * g];
        f32x4 uv1 = *(const f32x4*)&g_u[16 * r1 + 4 * g];
        f32x4 Ya0 = uv0, Yb0 = uv1;   // set 0, rows r0/r1
        f32x4 Ya1 = uv0, Yb1 = uv1;   // set 1
#pragma unroll
        for (int kc = 0; kc < 4; ++kc) {
            s16x8 af0 = *(const s16x8*)&lds_m[((r0 * 4 + kc) * 64 + l) * 8];
            s16x8 af1 = *(const s16x8*)&lds_m[((r1 * 4 + kc) * 64 + l) * 8];
            Ya0 = __builtin_amdgcn_mfma_f32_16x16x32_bf16(af0, rpf0[kc], Ya0, 0, 0, 0);
            Ya1 = __builtin_amdgcn_mfma_f32_16x16x32_bf16(af0, rpf1[kc], Ya1, 0, 0, 0);
            Yb0 = __builtin_amdgcn_mfma_f32_16x16x32_bf16(af1, rpf0[kc], Yb0, 0, 0, 0);
            Yb1 = __builtin_amdgcn_mfma_f32_16x16x32_bf16(af1, rpf1[kc], Yb1, 0, 0, 0);
        }
        s16x8 yf0 = mk8(pk2(Ya0[0], Ya0[1]), pk2(Ya0[2], Ya0[3]),
                        pk2(Yb0[0], Yb0[1]), pk2(Yb0[2], Yb0[3]));
        s16x8 yf1 = mk8(pk2(Ya1[0], Ya1[1]), pk2(Ya1[2], Ya1[3]),
                        pk2(Yb1[0], Yb1[1]), pk2(Yb1[2], Yb1[3]));
        Sacc0 = __builtin_amdgcn_mfma_f32_16x16x32_bf16(rpf0[rt], yf0, Sacc0, 0, 0, 0);
        Sacc1 = __builtin_amdgcn_mfma_f32_16x16x32_bf16(rpf1[rt], yf1, Sacc1, 0, 0, 0);
    }
    __builtin_amdgcn_s_setprio(0);

    __syncthreads();  // bar3: lds_gateP visible

    // ---- epilogue per column-set ----
    const int jv = c16 & 7;
    const bool diag = ((g >> 1) == np);
    auto do_epi = [&](const f32x4& Sacc, float sjv, float xvv, int s) {
        const int bp = wv * 4 + s * 2 + np;
        const long bt = base + bp;
        float Av[4], pr[4];
#pragma unroll
        for (int q = 0; q < 4; ++q) {
            float sc = (Sacc[q] + sjv + cc) * 0.08838834764831845f;
            unsigned wg = lds_gateP[bp * 33 + (4 * (g & 1) + q) * 4 + (jv >> 1)];
            float gv = __uint_as_float((jv & 1) ? (wg & 0xffff0000u) : (wg << 16));
            Av[q] = fast_tanh(sc) * gv;
            pr[q] = Av[q] * xvv;
            pr[q] += __shfl_xor(pr[q], 1);
            pr[q] += __shfl_xor(pr[q], 2);
            pr[q] += __shfl_xor(pr[q], 4);
        }
        if (diag) {
            float* Ap = A_out + bt * 64 + jv;
#pragma unroll
            for (int q = 0; q < 4; ++q) Ap[((g & 1) * 4 + q) * 8] = Av[q];
            if (jv == 0) {
                float* Pp = pred_out + bt * 8 + (g & 1) * 4;
#pragma unroll
                for (int q = 0; q < 4; ++q) Pp[q] = pr[q];
            }
        }
    };
    do_epi(Sacc0, sj0, xv0, 0);
    do_epi(Sacc1, sj1, xv1, 1);
}

extern "C" void kernel_launch(void* const* d_in, const int* in_sizes, int n_in,
                              void* d_out, int out_size, void* d_ws, size_t ws_size,
                              hipStream_t stream) {
    const float* x = (const float*)d_in[0];
    const float* hist = (const float*)d_in[1];
    const float* ce_w1 = (const float*)d_in[2];
    const float* ce_b1 = (const float*)d_in[3];
    const float* ce_w2 = (const float*)d_in[4];
    const float* ce_b2 = (const float*)d_in[5];
    const float* p_w1 = (const float*)d_in[6];
    const float* p_b1 = (const float*)d_in[7];
    const float* p_w2 = (const float*)d_in[8];
    const float* p_b2 = (const float*)d_in[9];
    const float* wq = (const float*)d_in[10];
    const float* wk = (const float*)d_in[11];

    float* pred_out = (float*)d_out;
    float* A_out = pred_out + (size_t)BTOT * 8;

    {
        void* args[] = {(void*)&wq, (void*)&wk, (void*)&p_w2, (void*)&p_b2,
                        (void*)&ce_w1, (void*)&ce_b1, (void*)&ce_w2};
        hipLaunchCooperativeKernel((const void*)k_pre_all, dim3(144), dim3(128),
                                   args, 0, stream);
    }
    k_fused<<<BTOT / 16, 256, 0, stream>>>(x, hist, ce_b2, p_w1, p_b1, pred_out, A_out);
}

// Round 20
// 59.418 us; speedup vs baseline: 1.5523x; 1.5523x over previous
//
#include <hip/hip_runtime.h>
#include <hip/hip_bf16.h>
#include <stdint.h>

#define Dm 128
#define BTOT (32 * 2048)

typedef short s16x8 __attribute__((ext_vector_type(8)));
typedef float f32x4 __attribute__((ext_vector_type(4)));

__device__ float g_Wq[Dm * Dm];   // Wq_c[g][d] = sum_f wq[g][f] * p_w2[f][d]
__device__ float g_Wk[Dm * Dm];
__device__ float g_bq[Dm], g_bk[Dm];
__device__ float g_u[Dm], g_w[Dm], g_c[1];
// frag buffer (shorts): [0,16384) M (32 slots), [16384,24576) W2f (16 slots), [24576,32768) W1f (16 slots)
__device__ __align__(16) unsigned short g_AllFrag[32768];

__device__ __forceinline__ float fast_sigmoid(float x) { return 1.0f / (1.0f + __expf(-x)); }
__device__ __forceinline__ float fast_tanh(float x) { return 1.0f - 2.0f / (__expf(2.0f * x) + 1.0f); }

__device__ __forceinline__ unsigned short f2bf(float f) {  // RNE f32->bf16 (precompute only)
    unsigned u = __float_as_uint(f);
    u += 0x7fffu + ((u >> 16) & 1u);
    return (unsigned short)(u >> 16);
}

__device__ __forceinline__ unsigned pk2(float lo, float hi) {  // 2×f32 -> packed 2×bf16 (RNE fptrunc)
    unsigned short ua = __builtin_bit_cast(unsigned short, (__bf16)lo);
    unsigned short ub = __builtin_bit_cast(unsigned short, (__bf16)hi);
    return (unsigned)ua | ((unsigned)ub << 16);
}

__device__ __forceinline__ s16x8 mk8(unsigned a, unsigned b, unsigned c, unsigned d) {
    union { unsigned u[4]; s16x8 v; } t;
    t.u[0] = a; t.u[1] = b; t.u[2] = c; t.u[3] = d;
    return t.v;
}

// rpf + sj for one wave's 2 positions (16 cols), k-map f(g,j)=4g+(j&3)+16*(j>>2).
__device__ __forceinline__ void compute_rpf(float xv, int g,
                                            const float* __restrict__ p_w1,
                                            const float* __restrict__ p_b1,
                                            s16x8* rpf, float& sj_out) {
    float sj = 0.f;
#pragma unroll
    for (int kc = 0; kc < 4; ++kc) {
        unsigned wds[4];
#pragma unroll
        for (int jh = 0; jh < 2; ++jh) {
            const int d4 = kc * 32 + 4 * g + 16 * jh;
            f32x4 w1v = *(const f32x4*)&p_w1[d4];
            f32x4 b1v = *(const f32x4*)&p_b1[d4];
            f32x4 wvv = *(const f32x4*)&g_w[d4];
            float v[4];
#pragma unroll
            for (int jj = 0; jj < 4; ++jj) {
                float val = fmaxf(fmaf(xv, w1v[jj], b1v[jj]), 0.f);
                sj = fmaf(wvv[jj], val, sj);
                v[jj] = val;
            }
            wds[jh * 2 + 0] = pk2(v[0], v[1]);
            wds[jh * 2 + 1] = pk2(v[2], v[3]);
        }
        rpf[kc] = mk8(wds[0], wds[1], wds[2], wds[3]);
    }
    sj += __shfl_xor(sj, 16);
    sj += __shfl_xor(sj, 32);
    sj_out = sj;
}

// blocks 0..127: combined Wq_c/Wk_c/bq/bk; 128..135: W1 frags (wide); 136..143: W2 frags (wide).
__global__ __launch_bounds__(128) void k_pre1(const float* __restrict__ wq,
                                              const float* __restrict__ wk,
                                              const float* __restrict__ pw2,
                                              const float* __restrict__ pb2,
                                              const float* __restrict__ ce_w1,
                                              const float* __restrict__ ce_b1,
                                              const float* __restrict__ ce_w2) {
    const int b = blockIdx.x, t = threadIdx.x;
    if (b < 128) {
        const int g = b, d = t;
        float aq0 = 0.f, aq1 = 0.f, ak0 = 0.f, ak1 = 0.f;
#pragma unroll 8
        for (int f2 = 0; f2 < 64; ++f2) {
            float wqa = wq[g * Dm + 2 * f2], wqb = wq[g * Dm + 2 * f2 + 1];
            float wka = wk[g * Dm + 2 * f2], wkb = wk[g * Dm + 2 * f2 + 1];
            float pva = pw2[(2 * f2) * Dm + d], pvb = pw2[(2 * f2 + 1) * Dm + d];
            aq0 = fmaf(wqa, pva, aq0);
            aq1 = fmaf(wqb, pvb, aq1);
            ak0 = fmaf(wka, pva, ak0);
            ak1 = fmaf(wkb, pvb, ak1);
        }
        g_Wq[g * Dm + d] = aq0 + aq1;
        g_Wk[g * Dm + d] = ak0 + ak1;
        if (d == 0) {
            float bq0 = 0.f, bq1 = 0.f, bk0 = 0.f, bk1 = 0.f;
#pragma unroll 8
            for (int f2 = 0; f2 < 64; ++f2) {
                float pba = pb2[2 * f2], pbb = pb2[2 * f2 + 1];
                bq0 = fmaf(wq[g * Dm + 2 * f2], pba, bq0);
                bq1 = fmaf(wq[g * Dm + 2 * f2 + 1], pbb, bq1);
                bk0 = fmaf(wk[g * Dm + 2 * f2], pba, bk0);
                bk1 = fmaf(wk[g * Dm + 2 * f2 + 1], pbb, bk1);
            }
            g_bq[g] = bq0 + bq1;
            g_bk[g] = bk0 + bk1;
        }
    } else if (b < 136) {
        // W1f: one s per thread; slot s = rt*2+kc; row = 16rt+(l&15); k = kc*32+4g+(j&3)+16*(j>>2)
        const int s = (b - 128) * 128 + t;   // 0..1023
        const int l = s & 63, slot = s >> 6;
        const int rt = slot >> 1, kc = slot & 1;
        const int row = rt * 16 + (l & 15), gg = l >> 4;
#pragma unroll
        for (int j = 0; j < 8; ++j) {
            int k = kc * 32 + 4 * gg + (j & 3) + 16 * (j >> 2);
            float v = (k < 40) ? ce_w1[row * 40 + k] : ((k == 40) ? ce_b1[row] : 0.f);
            g_AllFrag[24576 + s * 8 + j] = f2bf(v);
        }
    } else {
        // W2f: one s per thread; slot = rt2*4+kc; o = 16rt2+(l&15)
        const int s = (b - 136) * 128 + t;
        const int l = s & 63, slot = s >> 6;
        const int rt2 = slot >> 2, kc = slot & 3;
        const int o = rt2 * 16 + (l & 15), gg = l >> 4;
#pragma unroll
        for (int j = 0; j < 8; ++j) {
            int k = kc * 32 + 4 * gg + (j & 3) + 16 * (j >> 2);
            g_AllFrag[16384 + s * 8 + j] = f2bf(ce_w2[o * Dm + k]);
        }
    }
}

// blocks 0..127: M bf16 A-frags, one (slot,jj) per block (wide split); block 128: u/w/c.
__global__ __launch_bounds__(128) void k_pre2() {
    const int b = blockIdx.x, tid = threadIdx.x;
    if (b < 128) {
        const int slot = b >> 2, jj = b & 3;
        const int kc = slot & 3, rt = slot >> 2;
        const int l = tid & 63, jh = tid >> 6;
        const int row = rt * 16 + (l & 15), g = l >> 4;
        const int e = kc * 32 + 4 * g + jj + 16 * jh;
        float a0 = 0.f, a1 = 0.f;
#pragma unroll 8
        for (int g2 = 0; g2 < 64; ++g2) {
            a0 = fmaf(g_Wq[(2 * g2) * Dm + row], g_Wk[(2 * g2) * Dm + e], a0);
            a1 = fmaf(g_Wq[(2 * g2 + 1) * Dm + row], g_Wk[(2 * g2 + 1) * Dm + e], a1);
        }
        g_AllFrag[(slot * 64 + l) * 8 + 4 * jh + jj] = f2bf(a0 + a1);
    } else {
        const int d = tid;
        float u0 = 0.f, u1 = 0.f, w0 = 0.f, w1 = 0.f;
#pragma unroll 8
        for (int g2 = 0; g2 < 64; ++g2) {
            u0 = fmaf(g_Wq[(2 * g2) * Dm + d], g_bk[2 * g2], u0);
            u1 = fmaf(g_Wq[(2 * g2 + 1) * Dm + d], g_bk[2 * g2 + 1], u1);
            w0 = fmaf(g_Wk[(2 * g2) * Dm + d], g_bq[2 * g2], w0);
            w1 = fmaf(g_Wk[(2 * g2 + 1) * Dm + d], g_bq[2 * g2 + 1], w1);
        }
        g_u[d] = u0 + u1;
        g_w[d] = w0 + w1;
        if (d == 0) {
            float c0 = 0.f, c1 = 0.f;
#pragma unroll 8
            for (int g2 = 0; g2 < 64; ++g2) {
                c0 = fmaf(g_bq[2 * g2], g_bk[2 * g2], c0);
                c1 = fmaf(g_bq[2 * g2 + 1], g_bk[2 * g2 + 1], c1);
            }
            g_c[0] = c0 + c1;
        }
    }
}

// Fused kernel (round-17 best, frozen): 256 thr = 4 waves; 16 positions/block;
// each wave owns 4 positions (2 rpf column-sets); M in LDS; Y/S per row-pair
// (4 Yacc live); s_setprio around the Y/S MFMA cluster.
__global__ __launch_bounds__(256) void k_fused(const float* __restrict__ x,
                                               const float* __restrict__ hist,
                                               const float* __restrict__ ce_b2,
                                               const float* __restrict__ p_w1,
                                               const float* __restrict__ p_b1,
                                               float* __restrict__ pred_out,
                                               float* __restrict__ A_out) {
    __shared__ __align__(16) unsigned short lds_m[16384];  // M frags, 32 KB
    __shared__ __align__(16) unsigned short lds_hB[2048];  // h in gate-B-frag layout, 4 KB
    __shared__ __align__(16) char lds_hg[16 * 41 * 4];     // union: hist f32 [16][41] / gateP u32 [16][33]
    float* lds_hist = (float*)lds_hg;
    unsigned* lds_gateP = (unsigned*)lds_hg;

    const int tid = threadIdx.x;
    const int wv = tid >> 6;       // 0..3
    const int l = tid & 63;
    const int g = l >> 4, c16 = l & 15;
    const long base = (long)blockIdx.x * 16;

    // ---- stage M frags via DMA: 4 waves x 8 KB ----
    {
        const char* gsrc = (const char*)g_AllFrag + (size_t)wv * 8192 + (size_t)l * 16;
        char* ldst = (char*)lds_m + wv * 8192;
#pragma unroll
        for (int q = 0; q < 8; ++q)
            __builtin_amdgcn_global_load_lds(
                (const __attribute__((address_space(1))) unsigned int*)(gsrc + q * 1024),
                (__attribute__((address_space(3))) unsigned int*)(ldst + q * 1024), 16, 0, 0);
    }
    // ---- stage hist (640 floats) ----
    {
        const float* hsrc = hist + base * 40;
        lds_hist[(tid / 40) * 41 + (tid % 40)] = hsrc[tid];
        int i2 = tid + 256;
        lds_hist[(i2 / 40) * 41 + (i2 % 40)] = hsrc[i2];
        if (tid < 128) {
            int i3 = tid + 512;
            lds_hist[(i3 / 40) * 41 + (i3 % 40)] = hsrc[i3];
        }
    }
    // ---- W frags to regs (dead after gate phase) ----
    s16x8 w1fA[2][2];
#pragma unroll
    for (int rr = 0; rr < 2; ++rr)
#pragma unroll
        for (int kc = 0; kc < 2; ++kc)
            w1fA[rr][kc] = *(const s16x8*)&g_AllFrag[24576 + (((2 * wv + rr) * 2 + kc) * 64 + l) * 8];
    s16x8 w2fA[4];
#pragma unroll
    for (int kc = 0; kc < 4; ++kc)
        w2fA[kc] = *(const s16x8*)&g_AllFrag[16384 + ((wv * 4 + kc) * 64 + l) * 8];
    f32x4 b2v = *(const f32x4*)&ce_b2[16 * wv + 4 * g];

    // ---- rpf for both column-sets (positions wv*4 + s*2 + np) ----
    const int np = c16 >> 3, i_me = c16 & 7;
    const float xv0 = x[(base + wv * 4 + 0 + np) * 8 + i_me];
    const float xv1 = x[(base + wv * 4 + 2 + np) * 8 + i_me];
    s16x8 rpf0[4], rpf1[4];
    float sj0, sj1;
    compute_rpf(xv0, g, p_w1, p_b1, rpf0, sj0);
    compute_rpf(xv1, g, p_w1, p_b1, rpf1, sj1);
    const float cc = g_c[0];

    __syncthreads();  // bar1: M DMA drained, hist visible

    // ---- hist B-frags (cols = 16 block positions; bias-1 at k=40) ----
    const float* hl = lds_hist + c16 * 41;
    s16x8 histB[2];
    histB[0] = mk8(pk2(hl[4 * g + 0], hl[4 * g + 1]),
                   pk2(hl[4 * g + 2], hl[4 * g + 3]),
                   pk2(hl[16 + 4 * g + 0], hl[16 + 4 * g + 1]),
                   pk2(hl[16 + 4 * g + 2], hl[16 + 4 * g + 3]));
    {
        float v[4];
#pragma unroll
        for (int jj = 0; jj < 4; ++jj) {
            int k = 32 + 4 * g + jj;
            int kk = (k < 40) ? k : 0;
            float t = hl[kk];
            t = (k < 40) ? t : 0.f;
            v[jj] = (k == 40) ? 1.f : t;       // bias column
        }
        histB[1] = mk8(pk2(v[0], v[1]), pk2(v[2], v[3]), 0u, 0u);
    }

    // ---- h MFMA: row-tiles rt = 2wv+rr; publish relu(h) in gate-B-frag layout ----
#pragma unroll
    for (int rr = 0; rr < 2; ++rr) {
        f32x4 hC = (f32x4){0.f, 0.f, 0.f, 0.f};
        hC = __builtin_amdgcn_mfma_f32_16x16x32_bf16(w1fA[rr][0], histB[0], hC, 0, 0, 0);
        hC = __builtin_amdgcn_mfma_f32_16x16x32_bf16(w1fA[rr][1], histB[1], hC, 0, 0, 0);
        unsigned* dst = (unsigned*)&lds_hB[(wv * 64 + l) * 8 + rr * 4];
        dst[0] = pk2(fmaxf(hC[0], 0.f), fmaxf(hC[1], 0.f));
        dst[1] = pk2(fmaxf(hC[2], 0.f), fmaxf(hC[3], 0.f));
    }

    __syncthreads();  // bar2: hB visible; hist reads done -> gate may overwrite lds_hg

    // ---- gate MFMA: wave wv owns o-rows 16wv..16wv+15 -> packed bf16 lds_gateP ----
    {
        s16x8 gB[4];
#pragma unroll
        for (int kc = 0; kc < 4; ++kc)
            gB[kc] = *(const s16x8*)&lds_hB[(kc * 64 + l) * 8];
        f32x4 gC = b2v;
#pragma unroll
        for (int kc = 0; kc < 4; ++kc)
            gC = __builtin_amdgcn_mfma_f32_16x16x32_bf16(w2fA[kc], gB[kc], gC, 0, 0, 0);
        unsigned* gp = lds_gateP + c16 * 33 + 8 * wv + 2 * g;
        gp[0] = pk2(fast_sigmoid(gC[0]), fast_sigmoid(gC[1]));
        gp[1] = pk2(fast_sigmoid(gC[2]), fast_sigmoid(gC[3]));
    }

    // ---- Y/S fused per row-pair: only 4 Yacc live at a time (16 VGPR) ----
    __builtin_amdgcn_s_setprio(1);
    f32x4 Sacc0 = (f32x4){0.f, 0.f, 0.f, 0.f};
    f32x4 Sacc1 = (f32x4){0.f, 0.f, 0.f, 0.f};
#pragma unroll
    for (int rt = 0; rt < 4; ++rt) {
        const int r0 = 2 * rt, r1 = 2 * rt + 1;
        f32x4 uv0 = *(const f32x4*)&g_u[16 * r0 + 4 * g];
        f32x4 uv1 = *(const f32x4*)&g_u[16 * r1 + 4 * g];
        f32x4 Ya0 = uv0, Yb0 = uv1;   // set 0, rows r0/r1
        f32x4 Ya1 = uv0, Yb1 = uv1;   // set 1
#pragma unroll
        for (int kc = 0; kc < 4; ++kc) {
            s16x8 af0 = *(const s16x8*)&lds_m[((r0 * 4 + kc) * 64 + l) * 8];
            s16x8 af1 = *(const s16x8*)&lds_m[((r1 * 4 + kc) * 64 + l) * 8];
            Ya0 = __builtin_amdgcn_mfma_f32_16x16x32_bf16(af0, rpf0[kc], Ya0, 0, 0, 0);
            Ya1 = __builtin_amdgcn_mfma_f32_16x16x32_bf16(af0, rpf1[kc], Ya1, 0, 0, 0);
            Yb0 = __builtin_amdgcn_mfma_f32_16x16x32_bf16(af1, rpf0[kc], Yb0, 0, 0, 0);
            Yb1 = __builtin_amdgcn_mfma_f32_16x16x32_bf16(af1, rpf1[kc], Yb1, 0, 0, 0);
        }
        s16x8 yf0 = mk8(pk2(Ya0[0], Ya0[1]), pk2(Ya0[2], Ya0[3]),
                        pk2(Yb0[0], Yb0[1]), pk2(Yb0[2], Yb0[3]));
        s16x8 yf1 = mk8(pk2(Ya1[0], Ya1[1]), pk2(Ya1[2], Ya1[3]),
                        pk2(Yb1[0], Yb1[1]), pk2(Yb1[2], Yb1[3]));
        Sacc0 = __builtin_amdgcn_mfma_f32_16x16x32_bf16(rpf0[rt], yf0, Sacc0, 0, 0, 0);
        Sacc1 = __builtin_amdgcn_mfma_f32_16x16x32_bf16(rpf1[rt], yf1, Sacc1, 0, 0, 0);
    }
    __builtin_amdgcn_s_setprio(0);

    __syncthreads();  // bar3: lds_gateP visible

    // ---- epilogue per column-set ----
    const int jv = c16 & 7;
    const bool diag = ((g >> 1) == np);
    auto do_epi = [&](const f32x4& Sacc, float sjv, float xvv, int s) {
        const int bp = wv * 4 + s * 2 + np;
        const long bt = base + bp;
        float Av[4], pr[4];
#pragma unroll
        for (int q = 0; q < 4; ++q) {
            float sc = (Sacc[q] + sjv + cc) * 0.08838834764831845f;
            unsigned wg = lds_gateP[bp * 33 + (4 * (g & 1) + q) * 4 + (jv >> 1)];
            float gv = __uint_as_float((jv & 1) ? (wg & 0xffff0000u) : (wg << 16));
            Av[q] = fast_tanh(sc) * gv;
            pr[q] = Av[q] * xvv;
            pr[q] += __shfl_xor(pr[q], 1);
            pr[q] += __shfl_xor(pr[q], 2);
            pr[q] += __shfl_xor(pr[q], 4);
        }
        if (diag) {
            float* Ap = A_out + bt * 64 + jv;
#pragma unroll
            for (int q = 0; q < 4; ++q) Ap[((g & 1) * 4 + q) * 8] = Av[q];
            if (jv == 0) {
                float* Pp = pred_out + bt * 8 + (g & 1) * 4;
#pragma unroll
                for (int q = 0; q < 4; ++q) Pp[q] = pr[q];
            }
        }
    };
    do_epi(Sacc0, sj0, xv0, 0);
    do_epi(Sacc1, sj1, xv1, 1);
}

extern "C" void kernel_launch(void* const* d_in, const int* in_sizes, int n_in,
                              void* d_out, int out_size, void* d_ws, size_t ws_size,
                              hipStream_t stream) {
    const float* x = (const float*)d_in[0];
    const float* hist = (const float*)d_in[1];
    const float* ce_w1 = (const float*)d_in[2];
    const float* ce_b1 = (const float*)d_in[3];
    const float* ce_w2 = (const float*)d_in[4];
    const float* ce_b2 = (const float*)d_in[5];
    const float* p_w1 = (const float*)d_in[6];
    const float* p_b1 = (const float*)d_in[7];
    const float* p_w2 = (const float*)d_in[8];
    const float* p_b2 = (const float*)d_in[9];
    const float* wq = (const float*)d_in[10];
    const float* wk = (const float*)d_in[11];

    float* pred_out = (float*)d_out;
    float* A_out = pred_out + (size_t)BTOT * 8;

    k_pre1<<<144, 128, 0, stream>>>(wq, wk, p_w2, p_b2, ce_w1, ce_b1, ce_w2);
    k_pre2<<<129, 128, 0, stream>>>();
    k_fused<<<BTOT / 16, 256, 0, stream>>>(x, hist, ce_b2, p_w1, p_b1, pred_out, A_out);
}